// Round 15
// baseline (106.849 us; speedup 1.0000x reference)
//
#include <hip/hip_runtime.h>

typedef unsigned short u16;
typedef unsigned int u32;
typedef __attribute__((ext_vector_type(8))) short short8;   // 8 bf16 (MFMA A/B frag)
typedef __attribute__((ext_vector_type(4))) float f32x4;    // MFMA C/D frag
typedef __attribute__((ext_vector_type(4))) float fvec4;
typedef __attribute__((ext_vector_type(4))) u16 u16x4;

typedef __attribute__((address_space(1))) void gvoid;
typedef __attribute__((address_space(3))) void lvoid;

__device__ __forceinline__ u16 f2bf(float f) {
  u32 u = __float_as_uint(f);
  u += 0x7FFFu + ((u >> 16) & 1u);   // RTNE
  return (u16)(u >> 16);
}

// async global->LDS DMA, 16B/lane: LDS dest = uniform base + lane*16, global src per-lane.
__device__ __forceinline__ void gl16(const u16* g, u16* d) {
  __builtin_amdgcn_global_load_lds((gvoid*)g, (lvoid*)d, 16, 0, 0);
}

// wave-local LDS fence: drains this wave's ds ops only (lgkmcnt), does NOT touch vmcnt.
__device__ __forceinline__ void wave_lds_fence() {
  asm volatile("s_waitcnt lgkmcnt(0)" ::: "memory");
  __builtin_amdgcn_sched_barrier(0);
}

// memory row index of token (Bg,h,w); rows of x are 256 elems.
__device__ __forceinline__ int m_of(int Bg, int h, int w) {
  return ((Bg >> 2) << 14) | ((h & 3) << 12) | ((((Bg & 3) << 1) | (h >> 5)) << 9) |
         (((h >> 2) & 7) << 6) | w;
}

__device__ __forceinline__ f32x4 mfma16(short8 a, short8 b, f32x4 c) {
  return __builtin_amdgcn_mfma_f32_16x16x32_bf16(a, b, c, 0, 0, 0);
}

// qkvB blocked layout: element (channel c, token m) lives at (c>>2)*262144 + m*4 + (c&3).
__device__ __forceinline__ short8 ld8(const u16* __restrict__ qb, int c4, int m) {
  union { u16x4 h[2]; short8 v; } u;
  u.h[0] = *(const u16x4*)(qb + (size_t)c4 * 262144 + (size_t)m * 4);
  u.h[1] = *(const u16x4*)(qb + (size_t)(c4 + 1) * 262144 + (size_t)m * 4);
  return u.v;
}

// ---------------- prep: pack W into DMA-ready swizzled order + bias matrices --------------
// wbp layout: [(nh*8+chunk)*1536 + p]*8+e  where unit p holds col cu=(p>>2) and k-slot
// su=(p&3)^((cu>>1)&3): linear DMA order lands exactly in the swizzled LDS layout reads expect.
__global__ void k_prep(const float* __restrict__ qkv_w, const float* __restrict__ t0,
                       const float* __restrict__ t1, u16* __restrict__ wbp,
                       float* __restrict__ bias4, float* __restrict__ bias8) {
  int tid = blockIdx.x * 256 + threadIdx.x;
  int stride = gridDim.x * 256;
  for (int i = tid; i < 196608; i += stride) {
    int nhc = i / 12288;              // (nh*8 + chunk) in [0,16)
    int rem = i - nhc * 12288;
    int p = rem >> 3, e = rem & 7;
    int cu = p >> 2;
    int su = (p & 3) ^ ((cu >> 1) & 3);
    int col = (nhc >> 3) * 384 + cu;
    int k = (nhc & 7) * 32 + su * 8 + e;
    wbp[i] = f2bf(qkv_w[col * 256 + k]);
  }
  for (int i = tid; i < 4 * 64 * 64; i += stride) {
    int g = i >> 12, n = (i >> 6) & 63, m = i & 63;
    int di = (n >> 3) - (m >> 3) + 7, dj = (n & 7) - (m & 7) + 7;
    bias8[i] = t1[(di * 15 + dj) * 4 + g];
  }
  for (int i = tid; i < 4 * 16 * 16; i += stride) {
    int g = i >> 8, n = (i >> 4) & 15, m = i & 15;
    int di = (n >> 2) - (m >> 2) + 3, dj = (n & 3) - (m & 3) + 3;
    bias4[i] = t0[(di * 7 + dj) * 4 + g];
  }
}

// ---------------- QKV GEMM: [65536 x 256] x [256 x 768] -> qkvB blocked layout ------------
// Grid 2048: bid>>10 = col-half (384 cols), bid&1023 = 64-row m-tile. 8 waves; wave owns
// 48 cols x 64 rows. B via global_load_lds DMA (pre-swizzled wbp), per-wave double-buffered
// slabs, 2-DEEP COUNTED PIPELINE: iter ci waits vmcnt(3) (chunk ci is 2nd-newest in FIFO ->
// retired; chunk ci+1 stays in flight), reads, lgkm-drains (WAR-safe), issues chunk ci+2.
// All pre-loop VMEM (bias/xv/xp) is OLDER than in-loop DMAs -> counts order-robust. Bias
// pre-loaded & pinned at kernel top so the compiler cannot hoist epilogue loads into the
// counted window (round-13's suspected race). Raw s_barrier at K-half restage only.
__global__ __launch_bounds__(512, 4) void k_gemm(const float* __restrict__ x,
                                                 const u16* __restrict__ wbp,
                                                 const float* __restrict__ qkv_b,
                                                 u16* __restrict__ qkvB) {
  __shared__ __align__(16) u16 As[64 * 128];       // 16384 B, XOR slot-swizzled, K-half
  __shared__ __align__(16) u16 Bs[2 * 8 * 1536];   // 49152 B: [buf][wave][48 cols x 32 k]
  const int t = threadIdx.x;
  const int wid = t >> 6, l = t & 63;
  const int lr = l & 15, lk4 = l >> 4;
  const int mt = blockIdx.x & 1023, nh = blockIdx.x >> 10;
  const size_t xbase = (size_t)mt * 64 * 256;
  const int colbase = nh * 384;            // this block's first output col

  // B DMA geometry: src has per-lane l*8; dest base is wave-uniform (HW adds lane*16B)
  const u16* wsrc = wbp + (size_t)(nh * 8) * 12288 + (wid * 192 + l) * 8;
  u16* bdst = &Bs[wid * 1536];

  // A-stage unit mapping: 4 units/thread
  const int sr0 = t >> 5;                  // rows sr0, sr0+16, sr0+32, sr0+48
  const int scc = (t & 31) * 4;            // u16 col within 128-half
  const int sslot = scc >> 3, shalf = scc & 7;

  // ---- (1) bias pre-load: OLDEST VMEM, pinned before any DMA ----
  fvec4 bb[3];
#pragma unroll
  for (int jt = 0; jt < 3; ++jt)
    bb[jt] = *(const fvec4*)(qkv_b + colbase + wid * 48 + jt * 16 + lk4 * 4);
  asm volatile("" ::: "memory");           // bias loads stay above everything below

  // ---- (2) half1 x loads (consumed at the K-half boundary) ----
  fvec4 xv[4];
  {
    const float* xp1 = x + xbase + (size_t)sr0 * 256 + 128 + scc;
#pragma unroll
    for (int j = 0; j < 4; ++j) xv[j] = *(const fvec4*)(xp1 + j * 16 * 256);
  }
  // ---- (3) DMA chunk0 -> buf0, chunk1 -> buf1 ----
#pragma unroll
  for (int j = 0; j < 3; ++j) gl16(wsrc + j * 512, bdst + j * 512);
#pragma unroll
  for (int j = 0; j < 3; ++j) gl16(wsrc + 12288 + j * 512, bdst + 12288 + j * 512);
  asm volatile("" ::: "memory");           // pin DMA issue order before xp loads

  // ---- (4) stage A half0 (f32 loads -> cvt -> ds_write); consumption drains FIFO ----
  {
    const float* xp = x + xbase + (size_t)sr0 * 256 + scc;
#pragma unroll
    for (int j = 0; j < 4; ++j) {
      fvec4 v = *(const fvec4*)(xp + j * 16 * 256);
      int r = sr0 + j * 16;
      u16x4 u;
      u[0] = f2bf(v[0]); u[1] = f2bf(v[1]); u[2] = f2bf(v[2]); u[3] = f2bf(v[3]);
      *(u16x4*)&As[r * 128 + ((sslot ^ (r & 7)) << 3) + shalf] = u;
    }
  }
  asm volatile("s_waitcnt lgkmcnt(0)" ::: "memory");
  __builtin_amdgcn_s_barrier();            // As half0 visible

  f32x4 acc[3][4];
  const f32x4 z = {0.f, 0.f, 0.f, 0.f};
#pragma unroll
  for (int jt = 0; jt < 3; ++jt)
#pragma unroll
    for (int rt = 0; rt < 4; ++rt) acc[jt][rt] = z;

  const int bswz = (lr >> 1) & 3;          // B-read slot swizzle
#pragma unroll
  for (int ci = 0; ci < 8; ++ci) {
    if (ci == 4) {                         // K-half boundary: restage As from regs
      __builtin_amdgcn_s_barrier();        // all half0 reads retired (per-iter lgkm drains)
#pragma unroll
      for (int j = 0; j < 4; ++j) {
        int r = sr0 + j * 16;
        u16x4 u;
        u[0] = f2bf(xv[j][0]); u[1] = f2bf(xv[j][1]);
        u[2] = f2bf(xv[j][2]); u[3] = f2bf(xv[j][3]);
        *(u16x4*)&As[r * 128 + ((sslot ^ (r & 7)) << 3) + shalf] = u;
      }
      asm volatile("s_waitcnt lgkmcnt(0)" ::: "memory");
      __builtin_amdgcn_s_barrier();        // As half1 visible (DMAs stay in flight)
    }
    const int buf = ci & 1;
    // counted wait: chunk ci is 2nd-newest DMA group in FIFO -> vmcnt(3) retires it;
    // chunk ci+1 (newest, 3 ops) may stay in flight. Last iter: full drain.
    if (ci == 7) asm volatile("s_waitcnt vmcnt(0)" ::: "memory");
    else         asm volatile("s_waitcnt vmcnt(3)" ::: "memory");
    __builtin_amdgcn_sched_barrier(0);
    // reads (LDS only)
    short8 a[4], b[3];
    const int kslot = (ci & 3) * 4 + lk4;
#pragma unroll
    for (int rt = 0; rt < 4; ++rt) {
      int row = rt * 16 + lr;
      a[rt] = *(const short8*)&As[row * 128 + ((kslot ^ (row & 7)) << 3)];
    }
#pragma unroll
    for (int jt = 0; jt < 3; ++jt)
      b[jt] = *(const short8*)&Bs[buf * 12288 + wid * 1536 +
                                  (jt * 16 + lr) * 32 + ((lk4 ^ bswz) * 8)];
    // drain reads into regs -> WAR-safe to DMA into this buffer below
    asm volatile("s_waitcnt lgkmcnt(0)" ::: "memory");
    __builtin_amdgcn_sched_barrier(0);
    if (ci < 6) {                          // issue chunk ci+2 into buf(ci&1)
      const u16* s = wsrc + (size_t)(ci + 2) * 12288;
      u16* d = bdst + buf * 12288;
#pragma unroll
      for (int j = 0; j < 3; ++j) gl16(s + j * 512, d + j * 512);
    }
    __builtin_amdgcn_sched_barrier(0);
#pragma unroll
    for (int jt = 0; jt < 3; ++jt)
#pragma unroll
      for (int rt = 0; rt < 4; ++rt)
        acc[jt][rt] = mfma16(b[jt], a[rt], acc[jt][rt]);  // reg-dim = col
  }

  // ---- epilogue: + pre-loaded bias, blocked layout -> per-lane u16x4, coalesced ----
  const int rows0 = mt * 64;
#pragma unroll
  for (int jt = 0; jt < 3; ++jt) {
    int col0 = colbase + wid * 48 + jt * 16 + lk4 * 4;
    int c40 = col0 >> 2;
#pragma unroll
    for (int rt = 0; rt < 4; ++rt) {
      int row = rows0 + rt * 16 + lr;
      u16x4 u;
#pragma unroll
      for (int r = 0; r < 4; ++r) u[r] = f2bf(acc[jt][rt][r] + bb[jt][r]);
      *(u16x4*)&qkvB[(size_t)c40 * 262144 + (size_t)row * 4] = u;
    }
  }
}

// ---------------- attention ws=8 (group 1, channels 128..255) ----------------
// 1-wave blocks (grid 4096 = window x head), XCD-chunked swizzle; no barriers at all.
__global__ __launch_bounds__(64) void k_attn8(const u16* __restrict__ qkvB,
                                              const float* __restrict__ bias8,
                                              float* __restrict__ out) {
  __shared__ __align__(16) u16 vtg[32 * 72];  // V^T [e][m] (pad 8)
  __shared__ __align__(16) u16 plg[64 * 72];  // P [n][m]; reused as O f32 [64][33]
  const int lid = blockIdx.x;
  const int logical = (lid & 7) * 512 + (lid >> 3);  // bijective: 4096 = 8*512
  const int g = logical & 3;
  const int wj = (logical >> 2) & 7, wi = (logical >> 5) & 7, Bg = logical >> 8;
  const int h0 = wi * 8, w0 = wj * 8;
  const int l = threadIdx.x;
  const int lr = l & 15, lk4 = l >> 4;

  const int c4q = 32 + g * 8 + lk4 * 2;   // q chans 128+g*32+lk4*8
  const int c4k = 96 + g * 8 + lk4 * 2;   // k chans 384+g*32+lk4*8
  short8 aq[4], bk[4];
#pragma unroll
  for (int tn = 0; tn < 4; ++tn) {
    int n = tn * 16 + lr;
    int m = m_of(Bg, h0 + (n >> 3), w0 + (n & 7));
    aq[tn] = ld8(qkvB, c4q, m);
    bk[tn] = ld8(qkvB, c4k, m);
  }
  // stage V^T: lane l owns token m=l; v chans 640+g*32 .. +31 (8 c4-groups)
  {
    int m = m_of(Bg, h0 + (l >> 3), w0 + (l & 7));
#pragma unroll
    for (int j2 = 0; j2 < 8; ++j2) {
      u16x4 p = *(const u16x4*)(qkvB + (size_t)(160 + g * 8 + j2) * 262144 + (size_t)m * 4);
#pragma unroll
      for (int r = 0; r < 4; ++r) vtg[(j2 * 4 + r) * 72 + l] = p[r];
    }
  }
  // S = q k^T  (16 MFMAs)
  f32x4 z = {0.f, 0.f, 0.f, 0.f};
  f32x4 s[4][4];
#pragma unroll
  for (int tn = 0; tn < 4; ++tn)
#pragma unroll
    for (int tm = 0; tm < 4; ++tm) s[tn][tm] = mfma16(aq[tn], bk[tm], z);

  const float scale = 0.17677669529663687f;  // 1/sqrt(32)
#pragma unroll
  for (int tn = 0; tn < 4; ++tn)
#pragma unroll
    for (int tm = 0; tm < 4; ++tm)
#pragma unroll
      for (int r = 0; r < 4; ++r) {
        int n = tn * 16 + lk4 * 4 + r, m = tm * 16 + lr;
        s[tn][tm][r] = s[tn][tm][r] * scale + bias8[(g * 64 + n) * 64 + m];
      }
  // softmax over m (row n lives in 16 lanes sharing l>>4)
  float invden[4][4];
#pragma unroll
  for (int tn = 0; tn < 4; ++tn)
#pragma unroll
    for (int r = 0; r < 4; ++r) {
      float mx = fmaxf(fmaxf(s[tn][0][r], s[tn][1][r]), fmaxf(s[tn][2][r], s[tn][3][r]));
#pragma unroll
      for (int d = 1; d < 16; d <<= 1) mx = fmaxf(mx, __shfl_xor(mx, d));
      float sum = 0.f;
#pragma unroll
      for (int tm = 0; tm < 4; ++tm) {
        float p = __expf(s[tn][tm][r] - mx);
        s[tn][tm][r] = p;
        sum += p;
      }
#pragma unroll
      for (int d = 1; d < 16; d <<= 1) sum += __shfl_xor(sum, d);
      invden[tn][r] = 1.f / sum;
    }
  // P -> LDS (bf16)
#pragma unroll
  for (int tn = 0; tn < 4; ++tn)
#pragma unroll
    for (int tm = 0; tm < 4; ++tm)
#pragma unroll
      for (int r = 0; r < 4; ++r)
        plg[(tn * 16 + lk4 * 4 + r) * 72 + tm * 16 + lr] = f2bf(s[tn][tm][r]);
  wave_lds_fence();
  // O = P V  (16 MFMAs)
  f32x4 o[4][2];
#pragma unroll
  for (int tn = 0; tn < 4; ++tn) { o[tn][0] = z; o[tn][1] = z; }
#pragma unroll
  for (int kc = 0; kc < 2; ++kc) {
    short8 pa[4], vb[2];
#pragma unroll
    for (int tn = 0; tn < 4; ++tn)
      pa[tn] = *(const short8*)&plg[(tn * 16 + lr) * 72 + kc * 32 + lk4 * 8];
#pragma unroll
    for (int te = 0; te < 2; ++te)
      vb[te] = *(const short8*)&vtg[(te * 16 + lr) * 72 + kc * 32 + lk4 * 8];
#pragma unroll
    for (int tn = 0; tn < 4; ++tn)
#pragma unroll
      for (int te = 0; te < 2; ++te) o[tn][te] = mfma16(pa[tn], vb[te], o[tn][te]);
  }
  wave_lds_fence();
  // scale by 1/denom, transpose O through LDS (overlay on plg)
  float* ol = (float*)plg;  // [64][33]
#pragma unroll
  for (int tn = 0; tn < 4; ++tn)
#pragma unroll
    for (int te = 0; te < 2; ++te)
#pragma unroll
      for (int r = 0; r < 4; ++r) {
        int n = tn * 16 + lk4 * 4 + r;
        ol[n * 33 + te * 16 + lr] = o[tn][te][r] * invden[tn][r];
      }
  wave_lds_fence();
  // store: lane = token, loop e -> 32B-chunk runs along w (row-mates share XCD)
  {
    int h = h0 + (l >> 3), w = w0 + (l & 7);
    size_t base = ((size_t)(Bg >> 2)) * 4194304 + (size_t)(((Bg & 3) * 2 + (h >> 5))) * 131072 +
                  (size_t)(((h >> 2) & 7)) * 16384 + (size_t)((h & 3) * 64 + w);
#pragma unroll
    for (int e = 0; e < 32; ++e) {
      int c = 128 + g * 32 + e;
      size_t idx = base + (size_t)(c >> 6) * 1048576 + (size_t)((c >> 3) & 7) * 2048 +
                   (size_t)(c & 7) * 256;
      out[idx] = ol[l * 33 + e];
    }
  }
}

// ---------------- attention ws=4 (group 0, channels 0..127) ----------------
// block = 4 windows (1024 blocks), wave = window, heads looped; per-wave buffers -> no barriers
__global__ __launch_bounds__(256) void k_attn4(const u16* __restrict__ qkvB,
                                               const float* __restrict__ bias4,
                                               float* __restrict__ out) {
  __shared__ __align__(16) u16 vt[4 * 32 * 40];   // per-wave V^T [e][m0..32] (m 16..31 zero)
  __shared__ __align__(16) u16 pl[4 * 16 * 40];   // per-wave P [n][m0..32] (m 16..31 zero)
  __shared__ __align__(16) float ol[4 * 16 * 33]; // per-wave O
  int wv = threadIdx.x >> 6, l = threadIdx.x & 63;
  int wid = blockIdx.x * 4 + wv;
  int Bg = wid >> 8, wi = (wid >> 4) & 15, wj = wid & 15;
  int h0 = wi * 4, w0 = wj * 4;
  int lr = l & 15, lk4 = l >> 4;
  u16* vtw = vt + wv * (32 * 40);
  u16* plw = pl + wv * (16 * 40);
  float* olw = ol + wv * (16 * 33);
  f32x4 z = {0.f, 0.f, 0.f, 0.f};
  short8 z8 = {0, 0, 0, 0, 0, 0, 0, 0};
  const float scale = 0.17677669529663687f;

  // per-lane token index
  int hq = h0 + (lr >> 2), wq = w0 + (lr & 3);
  const int mq = m_of(Bg, hq, wq);

  for (int g = 0; g < 4; ++g) {
    short8 aq = ld8(qkvB, g * 8 + lk4 * 2, mq);          // q chans g*32+lk4*8
    short8 bk = ld8(qkvB, 64 + g * 8 + lk4 * 2, mq);     // k chans 256+g*32+lk4*8
    // stage V^T: lane = (token lr) x (e-chunk lk4)
    {
      short8 v = ld8(qkvB, 128 + g * 8 + lk4 * 2, mq);   // v chans 512+g*32+lk4*8
#pragma unroll
      for (int j = 0; j < 8; ++j) vtw[(lk4 * 8 + j) * 40 + lr] = (u16)v[j];
      // zero pad m in [16,32)
      *(short8*)&vtw[(l >> 1) * 40 + 16 + (l & 1) * 8] = z8;
    }
    // S (1 MFMA), C rows n = lk4*4+r, cols m = lr
    f32x4 s = mfma16(aq, bk, z);
#pragma unroll
    for (int r = 0; r < 4; ++r) {
      int n = lk4 * 4 + r;
      s[r] = s[r] * scale + bias4[(g * 16 + n) * 16 + lr];
    }
    float invden[4];
#pragma unroll
    for (int r = 0; r < 4; ++r) {
      float mx = s[r];
#pragma unroll
      for (int d = 1; d < 16; d <<= 1) mx = fmaxf(mx, __shfl_xor(mx, d));
      float p = __expf(s[r] - mx);
      s[r] = p;
      float sum = p;
#pragma unroll
      for (int d = 1; d < 16; d <<= 1) sum += __shfl_xor(sum, d);
      invden[r] = 1.f / sum;
    }
    // P -> LDS + zero pad
#pragma unroll
    for (int r = 0; r < 4; ++r) plw[(lk4 * 4 + r) * 40 + lr] = f2bf(s[r]);
    *(u16x4*)&plw[lr * 40 + 16 + lk4 * 4] = (u16x4){0, 0, 0, 0};
    wave_lds_fence();
    // O = P V : 2 MFMAs (te halves), K zero-padded to 32
    f32x4 o[2];
#pragma unroll
    for (int te = 0; te < 2; ++te) {
      short8 pa = *(const short8*)&plw[lr * 40 + lk4 * 8];
      short8 vb = *(const short8*)&vtw[(te * 16 + lr) * 40 + lk4 * 8];
      o[te] = mfma16(pa, vb, z);
    }
#pragma unroll
    for (int te = 0; te < 2; ++te)
#pragma unroll
      for (int r = 0; r < 4; ++r) {
        int n = lk4 * 4 + r;
        olw[n * 33 + te * 16 + lr] = o[te][r] * invden[r];
      }
    wave_lds_fence();
    // store: lane = (token lr) x (e-chunk lk4)
    {
      int h = h0 + (lr >> 2), w = w0 + (lr & 3);
      size_t base = ((size_t)(Bg >> 2)) * 4194304 +
                    (size_t)(((Bg & 3) * 2 + (h >> 5))) * 131072 +
                    (size_t)(((h >> 2) & 7)) * 16384 + (size_t)((h & 3) * 64 + w);
#pragma unroll
      for (int ee = 0; ee < 8; ++ee) {
        int e = lk4 * 8 + ee;
        int c = g * 32 + e;
        size_t idx = base + (size_t)(c >> 6) * 1048576 + (size_t)((c >> 3) & 7) * 2048 +
                     (size_t)(c & 7) * 256;
        out[idx] = olw[lr * 33 + e];
      }
    }
    wave_lds_fence();  // protect per-wave buffer reuse across g iterations
  }
}

extern "C" void kernel_launch(void* const* d_in, const int* in_sizes, int n_in,
                              void* d_out, int out_size, void* d_ws, size_t ws_size,
                              hipStream_t stream) {
  const float* x = (const float*)d_in[0];
  const float* qkv_w = (const float*)d_in[1];
  const float* qkv_b = (const float*)d_in[2];
  const float* t0 = (const float*)d_in[3];
  const float* t1 = (const float*)d_in[4];
  float* out = (float*)d_out;
  char* ws = (char*)d_ws;

  u16* qkvB = (u16*)ws;                         // 192*65536*4 u16  = 100663296 B
  u16* wbp = (u16*)(ws + 100663296);            // 196608 u16       = 393216 B
  float* bias8 = (float*)(ws + 101056512);      // 4*64*64*4        = 65536 B
  float* bias4 = (float*)(ws + 101122048);      // 4*16*16*4        = 4096 B

  k_prep<<<256, 256, 0, stream>>>(qkv_w, t0, t1, wbp, bias4, bias8);
  k_gemm<<<2048, 512, 0, stream>>>(x, wbp, qkv_b, qkvB);
  k_attn8<<<4096, 64, 0, stream>>>(qkvB, bias8, out);
  k_attn4<<<1024, 256, 0, stream>>>(qkvB, bias4, out);
}

// Round 16
// 98.135 us; speedup vs baseline: 1.0888x; 1.0888x over previous
//
#include <hip/hip_runtime.h>

typedef unsigned short u16;
typedef unsigned int u32;
typedef __attribute__((ext_vector_type(8))) short short8;   // 8 bf16 (MFMA A/B frag)
typedef __attribute__((ext_vector_type(4))) float f32x4;    // MFMA C/D frag
typedef __attribute__((ext_vector_type(4))) float fvec4;
typedef __attribute__((ext_vector_type(4))) u16 u16x4;

typedef __attribute__((address_space(1))) void gvoid;
typedef __attribute__((address_space(3))) void lvoid;

__device__ __forceinline__ u16 f2bf(float f) {
  u32 u = __float_as_uint(f);
  u += 0x7FFFu + ((u >> 16) & 1u);   // RTNE
  return (u16)(u >> 16);
}

// async global->LDS DMA, 16B/lane: LDS dest = uniform base + lane*16, global src per-lane.
__device__ __forceinline__ void gl16(const u16* g, u16* d) {
  __builtin_amdgcn_global_load_lds((gvoid*)g, (lvoid*)d, 16, 0, 0);
}

// wave-local LDS fence: drains this wave's ds ops only (lgkmcnt), does NOT touch vmcnt.
__device__ __forceinline__ void wave_lds_fence() {
  asm volatile("s_waitcnt lgkmcnt(0)" ::: "memory");
  __builtin_amdgcn_sched_barrier(0);
}

// memory row index of token (Bg,h,w); rows of x are 256 elems.
__device__ __forceinline__ int m_of(int Bg, int h, int w) {
  return ((Bg >> 2) << 14) | ((h & 3) << 12) | ((((Bg & 3) << 1) | (h >> 5)) << 9) |
         (((h >> 2) & 7) << 6) | w;
}

__device__ __forceinline__ f32x4 mfma16(short8 a, short8 b, f32x4 c) {
  return __builtin_amdgcn_mfma_f32_16x16x32_bf16(a, b, c, 0, 0, 0);
}

// qkvB blocked layout: element (channel c, token m) lives at (c>>2)*262144 + m*4 + (c&3).
__device__ __forceinline__ short8 ld8(const u16* __restrict__ qb, int c4, int m) {
  union { u16x4 h[2]; short8 v; } u;
  u.h[0] = *(const u16x4*)(qb + (size_t)c4 * 262144 + (size_t)m * 4);
  u.h[1] = *(const u16x4*)(qb + (size_t)(c4 + 1) * 262144 + (size_t)m * 4);
  return u.v;
}

// ---------------- prep: pack W into DMA-ready swizzled order + bias matrices --------------
__global__ void k_prep(const float* __restrict__ qkv_w, const float* __restrict__ t0,
                       const float* __restrict__ t1, u16* __restrict__ wbp,
                       float* __restrict__ bias4, float* __restrict__ bias8) {
  int tid = blockIdx.x * 256 + threadIdx.x;
  int stride = gridDim.x * 256;
  for (int i = tid; i < 196608; i += stride) {
    int nhc = i / 12288;              // (nh*8 + chunk) in [0,16)
    int rem = i - nhc * 12288;
    int p = rem >> 3, e = rem & 7;
    int cu = p >> 2;
    int su = (p & 3) ^ ((cu >> 1) & 3);
    int col = (nhc >> 3) * 384 + cu;
    int k = (nhc & 7) * 32 + su * 8 + e;
    wbp[i] = f2bf(qkv_w[col * 256 + k]);
  }
  for (int i = tid; i < 4 * 64 * 64; i += stride) {
    int g = i >> 12, n = (i >> 6) & 63, m = i & 63;
    int di = (n >> 3) - (m >> 3) + 7, dj = (n & 7) - (m & 7) + 7;
    bias8[i] = t1[(di * 15 + dj) * 4 + g];
  }
  for (int i = tid; i < 4 * 16 * 16; i += stride) {
    int g = i >> 8, n = (i >> 4) & 15, m = i & 15;
    int di = (n >> 2) - (m >> 2) + 3, dj = (n & 3) - (m & 3) + 3;
    bias4[i] = t0[(di * 7 + dj) * 4 + g];
  }
}

// ---------------- QKV GEMM: [65536 x 256] x [256 x 768] -> qkvB blocked layout ------------
// Grid 2048. PAIRING SWIZZLE: bids b and b+8 are the two col-halves (nh) of the SAME m-tile
// -> same XCD (round-robin mod 8), 8 dispatches apart -> second block's x-tile read is an
// XCD-L2 hit (halves x HBM traffic). Internals = round-15 (verified): DMA-B from
// pre-swizzled wbp, per-wave dbuf slabs, 2-deep counted vmcnt, bias/xv pinned pre-loop.
__global__ __launch_bounds__(512, 4) void k_gemm(const float* __restrict__ x,
                                                 const u16* __restrict__ wbp,
                                                 const float* __restrict__ qkv_b,
                                                 u16* __restrict__ qkvB) {
  __shared__ __align__(16) u16 As[64 * 128];       // 16384 B, XOR slot-swizzled, K-half
  __shared__ __align__(16) u16 Bs[2 * 8 * 1536];   // 49152 B: [buf][wave][48 cols x 32 k]
  const int t = threadIdx.x;
  const int wid = t >> 6, l = t & 63;
  const int lr = l & 15, lk4 = l >> 4;
  const int mt = ((blockIdx.x >> 4) << 3) | (blockIdx.x & 7);  // pairing swizzle
  const int nh = (blockIdx.x >> 3) & 1;
  const size_t xbase = (size_t)mt * 64 * 256;
  const int colbase = nh * 384;            // this block's first output col

  // B DMA geometry: src has per-lane l*8; dest base is wave-uniform (HW adds lane*16B)
  const u16* wsrc = wbp + (size_t)(nh * 8) * 12288 + (wid * 192 + l) * 8;
  u16* bdst = &Bs[wid * 1536];

  // A-stage unit mapping: 4 units/thread
  const int sr0 = t >> 5;                  // rows sr0, sr0+16, sr0+32, sr0+48
  const int scc = (t & 31) * 4;            // u16 col within 128-half
  const int sslot = scc >> 3, shalf = scc & 7;

  // ---- (1) bias pre-load: OLDEST VMEM, pinned before any DMA ----
  fvec4 bb[3];
#pragma unroll
  for (int jt = 0; jt < 3; ++jt)
    bb[jt] = *(const fvec4*)(qkv_b + colbase + wid * 48 + jt * 16 + lk4 * 4);
  asm volatile("" ::: "memory");           // bias loads stay above everything below

  // ---- (2) half1 x loads (consumed at the K-half boundary) ----
  fvec4 xv[4];
  {
    const float* xp1 = x + xbase + (size_t)sr0 * 256 + 128 + scc;
#pragma unroll
    for (int j = 0; j < 4; ++j) xv[j] = *(const fvec4*)(xp1 + j * 16 * 256);
  }
  // ---- (3) DMA chunk0 -> buf0, chunk1 -> buf1 ----
#pragma unroll
  for (int j = 0; j < 3; ++j) gl16(wsrc + j * 512, bdst + j * 512);
#pragma unroll
  for (int j = 0; j < 3; ++j) gl16(wsrc + 12288 + j * 512, bdst + 12288 + j * 512);
  asm volatile("" ::: "memory");           // pin DMA issue order before xp loads

  // ---- (4) stage A half0 (f32 loads -> cvt -> ds_write) ----
  {
    const float* xp = x + xbase + (size_t)sr0 * 256 + scc;
#pragma unroll
    for (int j = 0; j < 4; ++j) {
      fvec4 v = *(const fvec4*)(xp + j * 16 * 256);
      int r = sr0 + j * 16;
      u16x4 u;
      u[0] = f2bf(v[0]); u[1] = f2bf(v[1]); u[2] = f2bf(v[2]); u[3] = f2bf(v[3]);
      *(u16x4*)&As[r * 128 + ((sslot ^ (r & 7)) << 3) + shalf] = u;
    }
  }
  asm volatile("s_waitcnt lgkmcnt(0)" ::: "memory");
  __builtin_amdgcn_s_barrier();            // As half0 visible

  f32x4 acc[3][4];
  const f32x4 z = {0.f, 0.f, 0.f, 0.f};
#pragma unroll
  for (int jt = 0; jt < 3; ++jt)
#pragma unroll
    for (int rt = 0; rt < 4; ++rt) acc[jt][rt] = z;

  const int bswz = (lr >> 1) & 3;          // B-read slot swizzle
#pragma unroll
  for (int ci = 0; ci < 8; ++ci) {
    if (ci == 4) {                         // K-half boundary: restage As from regs
      __builtin_amdgcn_s_barrier();        // all half0 reads retired (per-iter lgkm drains)
#pragma unroll
      for (int j = 0; j < 4; ++j) {
        int r = sr0 + j * 16;
        u16x4 u;
        u[0] = f2bf(xv[j][0]); u[1] = f2bf(xv[j][1]);
        u[2] = f2bf(xv[j][2]); u[3] = f2bf(xv[j][3]);
        *(u16x4*)&As[r * 128 + ((sslot ^ (r & 7)) << 3) + shalf] = u;
      }
      asm volatile("s_waitcnt lgkmcnt(0)" ::: "memory");
      __builtin_amdgcn_s_barrier();        // As half1 visible (DMAs stay in flight)
    }
    const int buf = ci & 1;
    // counted wait: chunk ci is 2nd-newest DMA group in FIFO -> vmcnt(3) retires it.
    if (ci == 7) asm volatile("s_waitcnt vmcnt(0)" ::: "memory");
    else         asm volatile("s_waitcnt vmcnt(3)" ::: "memory");
    __builtin_amdgcn_sched_barrier(0);
    // reads (LDS only)
    short8 a[4], b[3];
    const int kslot = (ci & 3) * 4 + lk4;
#pragma unroll
    for (int rt = 0; rt < 4; ++rt) {
      int row = rt * 16 + lr;
      a[rt] = *(const short8*)&As[row * 128 + ((kslot ^ (row & 7)) << 3)];
    }
#pragma unroll
    for (int jt = 0; jt < 3; ++jt)
      b[jt] = *(const short8*)&Bs[buf * 12288 + wid * 1536 +
                                  (jt * 16 + lr) * 32 + ((lk4 ^ bswz) * 8)];
    // drain reads into regs -> WAR-safe to DMA into this buffer below
    asm volatile("s_waitcnt lgkmcnt(0)" ::: "memory");
    __builtin_amdgcn_sched_barrier(0);
    if (ci < 6) {                          // issue chunk ci+2 into buf(ci&1)
      const u16* s = wsrc + (size_t)(ci + 2) * 12288;
      u16* d = bdst + buf * 12288;
#pragma unroll
      for (int j = 0; j < 3; ++j) gl16(s + j * 512, d + j * 512);
    }
    __builtin_amdgcn_sched_barrier(0);
#pragma unroll
    for (int jt = 0; jt < 3; ++jt)
#pragma unroll
      for (int rt = 0; rt < 4; ++rt)
        acc[jt][rt] = mfma16(b[jt], a[rt], acc[jt][rt]);  // reg-dim = col
  }

  // ---- epilogue: + pre-loaded bias, blocked layout -> per-lane u16x4, coalesced ----
  const int rows0 = mt * 64;
#pragma unroll
  for (int jt = 0; jt < 3; ++jt) {
    int col0 = colbase + wid * 48 + jt * 16 + lk4 * 4;
    int c40 = col0 >> 2;
#pragma unroll
    for (int rt = 0; rt < 4; ++rt) {
      int row = rows0 + rt * 16 + lr;
      u16x4 u;
#pragma unroll
      for (int r = 0; r < 4; ++r) u[r] = f2bf(acc[jt][rt][r] + bb[jt][r]);
      *(u16x4*)&qkvB[(size_t)c40 * 262144 + (size_t)row * 4] = u;
    }
  }
}

// ---------------- attention ws=8 (group 1, channels 128..255) ----------------
// 1-wave blocks (grid 4096 = window x head), XCD-chunked swizzle; no barriers at all.
__global__ __launch_bounds__(64) void k_attn8(const u16* __restrict__ qkvB,
                                              const float* __restrict__ bias8,
                                              float* __restrict__ out) {
  __shared__ __align__(16) u16 vtg[32 * 72];  // V^T [e][m] (pad 8)
  __shared__ __align__(16) u16 plg[64 * 72];  // P [n][m]; reused as O f32 [64][33]
  const int lid = blockIdx.x;
  const int logical = (lid & 7) * 512 + (lid >> 3);  // bijective: 4096 = 8*512
  const int g = logical & 3;
  const int wj = (logical >> 2) & 7, wi = (logical >> 5) & 7, Bg = logical >> 8;
  const int h0 = wi * 8, w0 = wj * 8;
  const int l = threadIdx.x;
  const int lr = l & 15, lk4 = l >> 4;

  const int c4q = 32 + g * 8 + lk4 * 2;   // q chans 128+g*32+lk4*8
  const int c4k = 96 + g * 8 + lk4 * 2;   // k chans 384+g*32+lk4*8
  short8 aq[4], bk[4];
#pragma unroll
  for (int tn = 0; tn < 4; ++tn) {
    int n = tn * 16 + lr;
    int m = m_of(Bg, h0 + (n >> 3), w0 + (n & 7));
    aq[tn] = ld8(qkvB, c4q, m);
    bk[tn] = ld8(qkvB, c4k, m);
  }
  // stage V^T: lane l owns token m=l; v chans 640+g*32 .. +31 (8 c4-groups)
  {
    int m = m_of(Bg, h0 + (l >> 3), w0 + (l & 7));
#pragma unroll
    for (int j2 = 0; j2 < 8; ++j2) {
      u16x4 p = *(const u16x4*)(qkvB + (size_t)(160 + g * 8 + j2) * 262144 + (size_t)m * 4);
#pragma unroll
      for (int r = 0; r < 4; ++r) vtg[(j2 * 4 + r) * 72 + l] = p[r];
    }
  }
  // S = q k^T  (16 MFMAs)
  f32x4 z = {0.f, 0.f, 0.f, 0.f};
  f32x4 s[4][4];
#pragma unroll
  for (int tn = 0; tn < 4; ++tn)
#pragma unroll
    for (int tm = 0; tm < 4; ++tm) s[tn][tm] = mfma16(aq[tn], bk[tm], z);

  const float scale = 0.17677669529663687f;  // 1/sqrt(32)
#pragma unroll
  for (int tn = 0; tn < 4; ++tn)
#pragma unroll
    for (int tm = 0; tm < 4; ++tm)
#pragma unroll
      for (int r = 0; r < 4; ++r) {
        int n = tn * 16 + lk4 * 4 + r, m = tm * 16 + lr;
        s[tn][tm][r] = s[tn][tm][r] * scale + bias8[(g * 64 + n) * 64 + m];
      }
  // softmax over m (row n lives in 16 lanes sharing l>>4)
  float invden[4][4];
#pragma unroll
  for (int tn = 0; tn < 4; ++tn)
#pragma unroll
    for (int r = 0; r < 4; ++r) {
      float mx = fmaxf(fmaxf(s[tn][0][r], s[tn][1][r]), fmaxf(s[tn][2][r], s[tn][3][r]));
#pragma unroll
      for (int d = 1; d < 16; d <<= 1) mx = fmaxf(mx, __shfl_xor(mx, d));
      float sum = 0.f;
#pragma unroll
      for (int tm = 0; tm < 4; ++tm) {
        float p = __expf(s[tn][tm][r] - mx);
        s[tn][tm][r] = p;
        sum += p;
      }
#pragma unroll
      for (int d = 1; d < 16; d <<= 1) sum += __shfl_xor(sum, d);
      invden[tn][r] = 1.f / sum;
    }
  // P -> LDS (bf16)
#pragma unroll
  for (int tn = 0; tn < 4; ++tn)
#pragma unroll
    for (int tm = 0; tm < 4; ++tm)
#pragma unroll
      for (int r = 0; r < 4; ++r)
        plg[(tn * 16 + lk4 * 4 + r) * 72 + tm * 16 + lr] = f2bf(s[tn][tm][r]);
  wave_lds_fence();
  // O = P V  (16 MFMAs)
  f32x4 o[4][2];
#pragma unroll
  for (int tn = 0; tn < 4; ++tn) { o[tn][0] = z; o[tn][1] = z; }
#pragma unroll
  for (int kc = 0; kc < 2; ++kc) {
    short8 pa[4], vb[2];
#pragma unroll
    for (int tn = 0; tn < 4; ++tn)
      pa[tn] = *(const short8*)&plg[(tn * 16 + lr) * 72 + kc * 32 + lk4 * 8];
#pragma unroll
    for (int te = 0; te < 2; ++te)
      vb[te] = *(const short8*)&vtg[(te * 16 + lr) * 72 + kc * 32 + lk4 * 8];
#pragma unroll
    for (int tn = 0; tn < 4; ++tn)
#pragma unroll
      for (int te = 0; te < 2; ++te) o[tn][te] = mfma16(pa[tn], vb[te], o[tn][te]);
  }
  wave_lds_fence();
  // scale by 1/denom, transpose O through LDS (overlay on plg)
  float* ol = (float*)plg;  // [64][33]
#pragma unroll
  for (int tn = 0; tn < 4; ++tn)
#pragma unroll
    for (int te = 0; te < 2; ++te)
#pragma unroll
      for (int r = 0; r < 4; ++r) {
        int n = tn * 16 + lk4 * 4 + r;
        ol[n * 33 + te * 16 + lr] = o[tn][te][r] * invden[tn][r];
      }
  wave_lds_fence();
  // store: lane = token, loop e -> 32B-chunk runs along w (row-mates share XCD)
  {
    int h = h0 + (l >> 3), w = w0 + (l & 7);
    size_t base = ((size_t)(Bg >> 2)) * 4194304 + (size_t)(((Bg & 3) * 2 + (h >> 5))) * 131072 +
                  (size_t)(((h >> 2) & 7)) * 16384 + (size_t)((h & 3) * 64 + w);
#pragma unroll
    for (int e = 0; e < 32; ++e) {
      int c = 128 + g * 32 + e;
      size_t idx = base + (size_t)(c >> 6) * 1048576 + (size_t)((c >> 3) & 7) * 2048 +
                   (size_t)(c & 7) * 256;
      out[idx] = ol[l * 33 + e];
    }
  }
}

// ---------------- attention ws=4 (group 0, channels 0..127) ----------------
// ROUND-16: 1-wave blocks (grid 16384 = window x head), no g-loop, no barriers;
// XCD-chunked swizzle groups same-XCD work so adjacent-wj windows' out lines merge in L2.
__global__ __launch_bounds__(64) void k_attn4(const u16* __restrict__ qkvB,
                                              const float* __restrict__ bias4,
                                              float* __restrict__ out) {
  __shared__ __align__(16) u16 vtw[32 * 40];   // V^T [e][m0..32] (m 16..31 zero)
  __shared__ __align__(16) u16 plw[16 * 40];   // P [n][m0..32] (m 16..31 zero)
  __shared__ __align__(16) float olw[16 * 33]; // O
  const int lid = blockIdx.x;
  const int logical = (lid & 7) * 2048 + (lid >> 3);  // bijective: 16384 = 8*2048
  const int g = logical & 3;
  const int wid2 = logical >> 2;               // window id in [0,4096)
  const int Bg = wid2 >> 8, wi = (wid2 >> 4) & 15, wj = wid2 & 15;
  const int h0 = wi * 4, w0 = wj * 4;
  const int l = threadIdx.x;
  const int lr = l & 15, lk4 = l >> 4;
  const f32x4 z = {0.f, 0.f, 0.f, 0.f};
  const short8 z8 = {0, 0, 0, 0, 0, 0, 0, 0};
  const float scale = 0.17677669529663687f;

  // zero the K-padding (cols 16..31) of P and V^T
  {
    u16x4 z4 = {0, 0, 0, 0};
    *(u16x4*)&plw[(l & 15) * 40 + 16 + (l >> 4) * 4] = z4;
    *(short8*)&vtw[(l >> 1) * 40 + 16 + (l & 1) * 8] = z8;
  }
  // per-lane token index
  const int mq = m_of(Bg, h0 + (lr >> 2), w0 + (lr & 3));

  short8 aq = ld8(qkvB, g * 8 + lk4 * 2, mq);          // q chans g*32+lk4*8
  short8 bk = ld8(qkvB, 64 + g * 8 + lk4 * 2, mq);     // k chans 256+g*32+lk4*8
  // stage V^T: lane = (token lr) x (e-chunk lk4)
  {
    short8 v = ld8(qkvB, 128 + g * 8 + lk4 * 2, mq);   // v chans 512+g*32+lk4*8
#pragma unroll
    for (int j = 0; j < 8; ++j) vtw[(lk4 * 8 + j) * 40 + lr] = (u16)v[j];
  }
  // S (1 MFMA), C rows n = lk4*4+r, cols m = lr
  f32x4 s = mfma16(aq, bk, z);
#pragma unroll
  for (int r = 0; r < 4; ++r) {
    int n = lk4 * 4 + r;
    s[r] = s[r] * scale + bias4[(g * 16 + n) * 16 + lr];
  }
  float invden[4];
#pragma unroll
  for (int r = 0; r < 4; ++r) {
    float mx = s[r];
#pragma unroll
    for (int d = 1; d < 16; d <<= 1) mx = fmaxf(mx, __shfl_xor(mx, d));
    float p = __expf(s[r] - mx);
    s[r] = p;
    float sum = p;
#pragma unroll
    for (int d = 1; d < 16; d <<= 1) sum += __shfl_xor(sum, d);
    invden[r] = 1.f / sum;
  }
  // P -> LDS
#pragma unroll
  for (int r = 0; r < 4; ++r) plw[(lk4 * 4 + r) * 40 + lr] = f2bf(s[r]);
  wave_lds_fence();
  // O = P V : 2 MFMAs (te halves), K zero-padded to 32
  f32x4 o[2];
#pragma unroll
  for (int te = 0; te < 2; ++te) {
    short8 pa = *(const short8*)&plw[lr * 40 + lk4 * 8];
    short8 vb = *(const short8*)&vtw[(te * 16 + lr) * 40 + lk4 * 8];
    o[te] = mfma16(pa, vb, z);
  }
#pragma unroll
  for (int te = 0; te < 2; ++te)
#pragma unroll
    for (int r = 0; r < 4; ++r) {
      int n = lk4 * 4 + r;
      olw[n * 33 + te * 16 + lr] = o[te][r] * invden[r];
    }
  wave_lds_fence();
  // store: lane = (token lr) x (e-chunk lk4)
  {
    int h = h0 + (lr >> 2), w = w0 + (lr & 3);
    size_t base = ((size_t)(Bg >> 2)) * 4194304 +
                  (size_t)(((Bg & 3) * 2 + (h >> 5))) * 131072 +
                  (size_t)(((h >> 2) & 7)) * 16384 + (size_t)((h & 3) * 64 + w);
#pragma unroll
    for (int ee = 0; ee < 8; ++ee) {
      int e = lk4 * 8 + ee;
      int c = g * 32 + e;
      size_t idx = base + (size_t)(c >> 6) * 1048576 + (size_t)((c >> 3) & 7) * 2048 +
                   (size_t)(c & 7) * 256;
      out[idx] = olw[lr * 33 + e];
    }
  }
}

extern "C" void kernel_launch(void* const* d_in, const int* in_sizes, int n_in,
                              void* d_out, int out_size, void* d_ws, size_t ws_size,
                              hipStream_t stream) {
  const float* x = (const float*)d_in[0];
  const float* qkv_w = (const float*)d_in[1];
  const float* qkv_b = (const float*)d_in[2];
  const float* t0 = (const float*)d_in[3];
  const float* t1 = (const float*)d_in[4];
  float* out = (float*)d_out;
  char* ws = (char*)d_ws;

  u16* qkvB = (u16*)ws;                         // 192*65536*4 u16  = 100663296 B
  u16* wbp = (u16*)(ws + 100663296);            // 196608 u16       = 393216 B
  float* bias8 = (float*)(ws + 101056512);      // 4*64*64*4        = 65536 B
  float* bias4 = (float*)(ws + 101122048);      // 4*16*16*4        = 4096 B

  k_prep<<<256, 256, 0, stream>>>(qkv_w, t0, t1, wbp, bias4, bias8);
  k_gemm<<<2048, 512, 0, stream>>>(x, wbp, qkv_b, qkvB);
  k_attn8<<<4096, 64, 0, stream>>>(qkvB, bias8, out);
  k_attn4<<<16384, 64, 0, stream>>>(qkvB, bias4, out);
}

// Round 17
// 95.277 us; speedup vs baseline: 1.1215x; 1.0300x over previous
//
#include <hip/hip_runtime.h>

typedef unsigned short u16;
typedef unsigned int u32;
typedef __attribute__((ext_vector_type(8))) short short8;   // 8 bf16 (MFMA A/B frag)
typedef __attribute__((ext_vector_type(4))) float f32x4;    // MFMA C/D frag
typedef __attribute__((ext_vector_type(4))) float fvec4;
typedef __attribute__((ext_vector_type(4))) u16 u16x4;

typedef __attribute__((address_space(1))) void gvoid;
typedef __attribute__((address_space(3))) void lvoid;

__device__ __forceinline__ u16 f2bf(float f) {
  u32 u = __float_as_uint(f);
  u += 0x7FFFu + ((u >> 16) & 1u);   // RTNE
  return (u16)(u >> 16);
}

// async global->LDS DMA, 16B/lane: LDS dest = uniform base + lane*16, global src per-lane.
__device__ __forceinline__ void gl16(const u16* g, u16* d) {
  __builtin_amdgcn_global_load_lds((gvoid*)g, (lvoid*)d, 16, 0, 0);
}

// wave-local LDS fence: drains this wave's ds ops only (lgkmcnt), does NOT touch vmcnt.
__device__ __forceinline__ void wave_lds_fence() {
  asm volatile("s_waitcnt lgkmcnt(0)" ::: "memory");
  __builtin_amdgcn_sched_barrier(0);
}

// memory row index of token (Bg,h,w); rows of x are 256 elems.
__device__ __forceinline__ int m_of(int Bg, int h, int w) {
  return ((Bg >> 2) << 14) | ((h & 3) << 12) | ((((Bg & 3) << 1) | (h >> 5)) << 9) |
         (((h >> 2) & 7) << 6) | w;
}

__device__ __forceinline__ f32x4 mfma16(short8 a, short8 b, f32x4 c) {
  return __builtin_amdgcn_mfma_f32_16x16x32_bf16(a, b, c, 0, 0, 0);
}

// qkvB blocked layout: element (channel c, token m) lives at (c>>2)*262144 + m*4 + (c&3).
__device__ __forceinline__ short8 ld8(const u16* __restrict__ qb, int c4, int m) {
  union { u16x4 h[2]; short8 v; } u;
  u.h[0] = *(const u16x4*)(qb + (size_t)c4 * 262144 + (size_t)m * 4);
  u.h[1] = *(const u16x4*)(qb + (size_t)(c4 + 1) * 262144 + (size_t)m * 4);
  return u.v;
}

// ---------------- prep: pack W into DMA-ready swizzled order + bias matrices --------------
__global__ void k_prep(const float* __restrict__ qkv_w, const float* __restrict__ t0,
                       const float* __restrict__ t1, u16* __restrict__ wbp,
                       float* __restrict__ bias4, float* __restrict__ bias8) {
  int tid = blockIdx.x * 256 + threadIdx.x;
  int stride = gridDim.x * 256;
  for (int i = tid; i < 196608; i += stride) {
    int nhc = i / 12288;              // (nh*8 + chunk) in [0,16)
    int rem = i - nhc * 12288;
    int p = rem >> 3, e = rem & 7;
    int cu = p >> 2;
    int su = (p & 3) ^ ((cu >> 1) & 3);
    int col = (nhc >> 3) * 384 + cu;
    int k = (nhc & 7) * 32 + su * 8 + e;
    wbp[i] = f2bf(qkv_w[col * 256 + k]);
  }
  for (int i = tid; i < 4 * 64 * 64; i += stride) {
    int g = i >> 12, n = (i >> 6) & 63, m = i & 63;
    int di = (n >> 3) - (m >> 3) + 7, dj = (n & 7) - (m & 7) + 7;
    bias8[i] = t1[(di * 15 + dj) * 4 + g];
  }
  for (int i = tid; i < 4 * 16 * 16; i += stride) {
    int g = i >> 8, n = (i >> 4) & 15, m = i & 15;
    int di = (n >> 2) - (m >> 2) + 3, dj = (n & 3) - (m & 3) + 3;
    bias4[i] = t0[(di * 7 + dj) * 4 + g];
  }
}

// ---------------- QKV GEMM: [65536 x 256] x [256 x 768] -> qkvB blocked layout ------------
// Grid 2048, pairing swizzle (col-half pairs share an XCD -> x tile L2-hit). DMA-B from
// pre-swizzled wbp, per-wave dbuf slabs, 2-deep counted vmcnt(3). ROUND-17: xv half1
// prefetch DROPPED (-16 VGPR -> ~92 total incl acc -> 5 waves/SIMD); x half1 is re-read
// from L2 at the K-half boundary, pinned by sched_barriers so it cannot hoist into the
// counted-vmcnt window (r13 lesson). Bias pre-loaded & pinned at top (oldest VMEM).
__global__ __launch_bounds__(512, 4) void k_gemm(const float* __restrict__ x,
                                                 const u16* __restrict__ wbp,
                                                 const float* __restrict__ qkv_b,
                                                 u16* __restrict__ qkvB) {
  __shared__ __align__(16) u16 As[64 * 128];       // 16384 B, XOR slot-swizzled, K-half
  __shared__ __align__(16) u16 Bs[2 * 8 * 1536];   // 49152 B: [buf][wave][48 cols x 32 k]
  const int t = threadIdx.x;
  const int wid = t >> 6, l = t & 63;
  const int lr = l & 15, lk4 = l >> 4;
  const int mt = ((blockIdx.x >> 4) << 3) | (blockIdx.x & 7);  // pairing swizzle
  const int nh = (blockIdx.x >> 3) & 1;
  const size_t xbase = (size_t)mt * 64 * 256;
  const int colbase = nh * 384;            // this block's first output col

  // B DMA geometry: src has per-lane l*8; dest base is wave-uniform (HW adds lane*16B)
  const u16* wsrc = wbp + (size_t)(nh * 8) * 12288 + (wid * 192 + l) * 8;
  u16* bdst = &Bs[wid * 1536];

  // A-stage unit mapping: 4 units/thread
  const int sr0 = t >> 5;                  // rows sr0, sr0+16, sr0+32, sr0+48
  const int scc = (t & 31) * 4;            // u16 col within 128-half
  const int sslot = scc >> 3, shalf = scc & 7;

  // ---- (1) bias pre-load: OLDEST VMEM, pinned before any DMA ----
  fvec4 bb[3];
#pragma unroll
  for (int jt = 0; jt < 3; ++jt)
    bb[jt] = *(const fvec4*)(qkv_b + colbase + wid * 48 + jt * 16 + lk4 * 4);
  asm volatile("" ::: "memory");           // bias loads stay above everything below

  // ---- (2) DMA chunk0 -> buf0, chunk1 -> buf1 ----
#pragma unroll
  for (int j = 0; j < 3; ++j) gl16(wsrc + j * 512, bdst + j * 512);
#pragma unroll
  for (int j = 0; j < 3; ++j) gl16(wsrc + 12288 + j * 512, bdst + 12288 + j * 512);
  asm volatile("" ::: "memory");           // pin DMA issue order before xp loads

  // ---- (3) stage A half0 (f32 loads -> cvt -> ds_write) ----
  {
    const float* xp = x + xbase + (size_t)sr0 * 256 + scc;
#pragma unroll
    for (int j = 0; j < 4; ++j) {
      fvec4 v = *(const fvec4*)(xp + j * 16 * 256);
      int r = sr0 + j * 16;
      u16x4 u;
      u[0] = f2bf(v[0]); u[1] = f2bf(v[1]); u[2] = f2bf(v[2]); u[3] = f2bf(v[3]);
      *(u16x4*)&As[r * 128 + ((sslot ^ (r & 7)) << 3) + shalf] = u;
    }
  }
  asm volatile("s_waitcnt lgkmcnt(0)" ::: "memory");
  __builtin_amdgcn_s_barrier();            // As half0 visible

  f32x4 acc[3][4];
  const f32x4 z = {0.f, 0.f, 0.f, 0.f};
#pragma unroll
  for (int jt = 0; jt < 3; ++jt)
#pragma unroll
    for (int rt = 0; rt < 4; ++rt) acc[jt][rt] = z;

  const int bswz = (lr >> 1) & 3;          // B-read slot swizzle
#pragma unroll
  for (int ci = 0; ci < 8; ++ci) {
    if (ci == 4) {                         // K-half boundary: restage As from L2-hot x
      __builtin_amdgcn_s_barrier();        // all half0 reads retired (per-iter lgkm drains)
      __builtin_amdgcn_sched_barrier(0);   // no hoisting of the loads below into iters 0-3
      {
        const float* xp1 = x + xbase + (size_t)sr0 * 256 + 128 + scc;
#pragma unroll
        for (int j = 0; j < 4; ++j) {
          fvec4 v = *(const fvec4*)(xp1 + j * 16 * 256);  // compiler-inserted vmcnt drains
          int r = sr0 + j * 16;                           // DMA chunks 4,5 early (safe)
          u16x4 u;
          u[0] = f2bf(v[0]); u[1] = f2bf(v[1]); u[2] = f2bf(v[2]); u[3] = f2bf(v[3]);
          *(u16x4*)&As[r * 128 + ((sslot ^ (r & 7)) << 3) + shalf] = u;
        }
      }
      asm volatile("s_waitcnt lgkmcnt(0)" ::: "memory");
      __builtin_amdgcn_sched_barrier(0);   // no sinking of loads below this point either
      __builtin_amdgcn_s_barrier();        // As half1 visible
    }
    const int buf = ci & 1;
    // counted wait: chunk ci is the 2nd-newest DMA group in FIFO -> vmcnt(3) retires it
    // (post-boundary: chunks 4,5 already drained; count still conservative-correct).
    if (ci == 7) asm volatile("s_waitcnt vmcnt(0)" ::: "memory");
    else         asm volatile("s_waitcnt vmcnt(3)" ::: "memory");
    __builtin_amdgcn_sched_barrier(0);
    // reads (LDS only)
    short8 a[4], b[3];
    const int kslot = (ci & 3) * 4 + lk4;
#pragma unroll
    for (int rt = 0; rt < 4; ++rt) {
      int row = rt * 16 + lr;
      a[rt] = *(const short8*)&As[row * 128 + ((kslot ^ (row & 7)) << 3)];
    }
#pragma unroll
    for (int jt = 0; jt < 3; ++jt)
      b[jt] = *(const short8*)&Bs[buf * 12288 + wid * 1536 +
                                  (jt * 16 + lr) * 32 + ((lk4 ^ bswz) * 8)];
    // drain reads into regs -> WAR-safe to DMA into this buffer below
    asm volatile("s_waitcnt lgkmcnt(0)" ::: "memory");
    __builtin_amdgcn_sched_barrier(0);
    if (ci < 6) {                          // issue chunk ci+2 into buf(ci&1)
      const u16* s = wsrc + (size_t)(ci + 2) * 12288;
      u16* d = bdst + buf * 12288;
#pragma unroll
      for (int j = 0; j < 3; ++j) gl16(s + j * 512, d + j * 512);
    }
    __builtin_amdgcn_sched_barrier(0);
#pragma unroll
    for (int jt = 0; jt < 3; ++jt)
#pragma unroll
      for (int rt = 0; rt < 4; ++rt)
        acc[jt][rt] = mfma16(b[jt], a[rt], acc[jt][rt]);  // reg-dim = col
  }

  // ---- epilogue: + pre-loaded bias, blocked layout -> per-lane u16x4, coalesced ----
  const int rows0 = mt * 64;
#pragma unroll
  for (int jt = 0; jt < 3; ++jt) {
    int col0 = colbase + wid * 48 + jt * 16 + lk4 * 4;
    int c40 = col0 >> 2;
#pragma unroll
    for (int rt = 0; rt < 4; ++rt) {
      int row = rows0 + rt * 16 + lr;
      u16x4 u;
#pragma unroll
      for (int r = 0; r < 4; ++r) u[r] = f2bf(acc[jt][rt][r] + bb[jt][r]);
      *(u16x4*)&qkvB[(size_t)c40 * 262144 + (size_t)row * 4] = u;
    }
  }
}

// ---------------- attention ws=8 (group 1, channels 128..255) ----------------
// 1-wave blocks (grid 4096 = window x head), XCD-chunked swizzle; no barriers at all.
__global__ __launch_bounds__(64) void k_attn8(const u16* __restrict__ qkvB,
                                              const float* __restrict__ bias8,
                                              float* __restrict__ out) {
  __shared__ __align__(16) u16 vtg[32 * 72];  // V^T [e][m] (pad 8)
  __shared__ __align__(16) u16 plg[64 * 72];  // P [n][m]; reused as O f32 [64][33]
  const int lid = blockIdx.x;
  const int logical = (lid & 7) * 512 + (lid >> 3);  // bijective: 4096 = 8*512
  const int g = logical & 3;
  const int wj = (logical >> 2) & 7, wi = (logical >> 5) & 7, Bg = logical >> 8;
  const int h0 = wi * 8, w0 = wj * 8;
  const int l = threadIdx.x;
  const int lr = l & 15, lk4 = l >> 4;

  const int c4q = 32 + g * 8 + lk4 * 2;   // q chans 128+g*32+lk4*8
  const int c4k = 96 + g * 8 + lk4 * 2;   // k chans 384+g*32+lk4*8
  short8 aq[4], bk[4];
#pragma unroll
  for (int tn = 0; tn < 4; ++tn) {
    int n = tn * 16 + lr;
    int m = m_of(Bg, h0 + (n >> 3), w0 + (n & 7));
    aq[tn] = ld8(qkvB, c4q, m);
    bk[tn] = ld8(qkvB, c4k, m);
  }
  // stage V^T: lane l owns token m=l; v chans 640+g*32 .. +31 (8 c4-groups)
  {
    int m = m_of(Bg, h0 + (l >> 3), w0 + (l & 7));
#pragma unroll
    for (int j2 = 0; j2 < 8; ++j2) {
      u16x4 p = *(const u16x4*)(qkvB + (size_t)(160 + g * 8 + j2) * 262144 + (size_t)m * 4);
#pragma unroll
      for (int r = 0; r < 4; ++r) vtg[(j2 * 4 + r) * 72 + l] = p[r];
    }
  }
  // S = q k^T  (16 MFMAs)
  f32x4 z = {0.f, 0.f, 0.f, 0.f};
  f32x4 s[4][4];
#pragma unroll
  for (int tn = 0; tn < 4; ++tn)
#pragma unroll
    for (int tm = 0; tm < 4; ++tm) s[tn][tm] = mfma16(aq[tn], bk[tm], z);

  const float scale = 0.17677669529663687f;  // 1/sqrt(32)
#pragma unroll
  for (int tn = 0; tn < 4; ++tn)
#pragma unroll
    for (int tm = 0; tm < 4; ++tm)
#pragma unroll
      for (int r = 0; r < 4; ++r) {
        int n = tn * 16 + lk4 * 4 + r, m = tm * 16 + lr;
        s[tn][tm][r] = s[tn][tm][r] * scale + bias8[(g * 64 + n) * 64 + m];
      }
  // softmax over m (row n lives in 16 lanes sharing l>>4)
  float invden[4][4];
#pragma unroll
  for (int tn = 0; tn < 4; ++tn)
#pragma unroll
    for (int r = 0; r < 4; ++r) {
      float mx = fmaxf(fmaxf(s[tn][0][r], s[tn][1][r]), fmaxf(s[tn][2][r], s[tn][3][r]));
#pragma unroll
      for (int d = 1; d < 16; d <<= 1) mx = fmaxf(mx, __shfl_xor(mx, d));
      float sum = 0.f;
#pragma unroll
      for (int tm = 0; tm < 4; ++tm) {
        float p = __expf(s[tn][tm][r] - mx);
        s[tn][tm][r] = p;
        sum += p;
      }
#pragma unroll
      for (int d = 1; d < 16; d <<= 1) sum += __shfl_xor(sum, d);
      invden[tn][r] = 1.f / sum;
    }
  // P -> LDS (bf16)
#pragma unroll
  for (int tn = 0; tn < 4; ++tn)
#pragma unroll
    for (int tm = 0; tm < 4; ++tm)
#pragma unroll
      for (int r = 0; r < 4; ++r)
        plg[(tn * 16 + lk4 * 4 + r) * 72 + tm * 16 + lr] = f2bf(s[tn][tm][r]);
  wave_lds_fence();
  // O = P V  (16 MFMAs)
  f32x4 o[4][2];
#pragma unroll
  for (int tn = 0; tn < 4; ++tn) { o[tn][0] = z; o[tn][1] = z; }
#pragma unroll
  for (int kc = 0; kc < 2; ++kc) {
    short8 pa[4], vb[2];
#pragma unroll
    for (int tn = 0; tn < 4; ++tn)
      pa[tn] = *(const short8*)&plg[(tn * 16 + lr) * 72 + kc * 32 + lk4 * 8];
#pragma unroll
    for (int te = 0; te < 2; ++te)
      vb[te] = *(const short8*)&vtg[(te * 16 + lr) * 72 + kc * 32 + lk4 * 8];
#pragma unroll
    for (int tn = 0; tn < 4; ++tn)
#pragma unroll
      for (int te = 0; te < 2; ++te) o[tn][te] = mfma16(pa[tn], vb[te], o[tn][te]);
  }
  wave_lds_fence();
  // scale by 1/denom, transpose O through LDS (overlay on plg)
  float* ol = (float*)plg;  // [64][33]
#pragma unroll
  for (int tn = 0; tn < 4; ++tn)
#pragma unroll
    for (int te = 0; te < 2; ++te)
#pragma unroll
      for (int r = 0; r < 4; ++r) {
        int n = tn * 16 + lk4 * 4 + r;
        ol[n * 33 + te * 16 + lr] = o[tn][te][r] * invden[tn][r];
      }
  wave_lds_fence();
  // store: lane = token, loop e -> 32B-chunk runs along w (row-mates share XCD)
  {
    int h = h0 + (l >> 3), w = w0 + (l & 7);
    size_t base = ((size_t)(Bg >> 2)) * 4194304 + (size_t)(((Bg & 3) * 2 + (h >> 5))) * 131072 +
                  (size_t)(((h >> 2) & 7)) * 16384 + (size_t)((h & 3) * 64 + w);
#pragma unroll
    for (int e = 0; e < 32; ++e) {
      int c = 128 + g * 32 + e;
      size_t idx = base + (size_t)(c >> 6) * 1048576 + (size_t)((c >> 3) & 7) * 2048 +
                   (size_t)(c & 7) * 256;
      out[idx] = ol[l * 33 + e];
    }
  }
}

// ---------------- attention ws=4 (group 0, channels 0..127) ----------------
// 1-wave blocks (grid 16384 = window x head), no g-loop, no barriers; XCD-chunked swizzle.
__global__ __launch_bounds__(64) void k_attn4(const u16* __restrict__ qkvB,
                                              const float* __restrict__ bias4,
                                              float* __restrict__ out) {
  __shared__ __align__(16) u16 vtw[32 * 40];   // V^T [e][m0..32] (m 16..31 zero)
  __shared__ __align__(16) u16 plw[16 * 40];   // P [n][m0..32] (m 16..31 zero)
  __shared__ __align__(16) float olw[16 * 33]; // O
  const int lid = blockIdx.x;
  const int logical = (lid & 7) * 2048 + (lid >> 3);  // bijective: 16384 = 8*2048
  const int g = logical & 3;
  const int wid2 = logical >> 2;               // window id in [0,4096)
  const int Bg = wid2 >> 8, wi = (wid2 >> 4) & 15, wj = wid2 & 15;
  const int h0 = wi * 4, w0 = wj * 4;
  const int l = threadIdx.x;
  const int lr = l & 15, lk4 = l >> 4;
  const f32x4 z = {0.f, 0.f, 0.f, 0.f};
  const short8 z8 = {0, 0, 0, 0, 0, 0, 0, 0};
  const float scale = 0.17677669529663687f;

  // zero the K-padding (cols 16..31) of P and V^T
  {
    u16x4 z4 = {0, 0, 0, 0};
    *(u16x4*)&plw[(l & 15) * 40 + 16 + (l >> 4) * 4] = z4;
    *(short8*)&vtw[(l >> 1) * 40 + 16 + (l & 1) * 8] = z8;
  }
  // per-lane token index
  const int mq = m_of(Bg, h0 + (lr >> 2), w0 + (lr & 3));

  short8 aq = ld8(qkvB, g * 8 + lk4 * 2, mq);          // q chans g*32+lk4*8
  short8 bk = ld8(qkvB, 64 + g * 8 + lk4 * 2, mq);     // k chans 256+g*32+lk4*8
  // stage V^T: lane = (token lr) x (e-chunk lk4)
  {
    short8 v = ld8(qkvB, 128 + g * 8 + lk4 * 2, mq);   // v chans 512+g*32+lk4*8
#pragma unroll
    for (int j = 0; j < 8; ++j) vtw[(lk4 * 8 + j) * 40 + lr] = (u16)v[j];
  }
  // S (1 MFMA), C rows n = lk4*4+r, cols m = lr
  f32x4 s = mfma16(aq, bk, z);
#pragma unroll
  for (int r = 0; r < 4; ++r) {
    int n = lk4 * 4 + r;
    s[r] = s[r] * scale + bias4[(g * 16 + n) * 16 + lr];
  }
  float invden[4];
#pragma unroll
  for (int r = 0; r < 4; ++r) {
    float mx = s[r];
#pragma unroll
    for (int d = 1; d < 16; d <<= 1) mx = fmaxf(mx, __shfl_xor(mx, d));
    float p = __expf(s[r] - mx);
    s[r] = p;
    float sum = p;
#pragma unroll
    for (int d = 1; d < 16; d <<= 1) sum += __shfl_xor(sum, d);
    invden[r] = 1.f / sum;
  }
  // P -> LDS
#pragma unroll
  for (int r = 0; r < 4; ++r) plw[(lk4 * 4 + r) * 40 + lr] = f2bf(s[r]);
  wave_lds_fence();
  // O = P V : 2 MFMAs (te halves), K zero-padded to 32
  f32x4 o[2];
#pragma unroll
  for (int te = 0; te < 2; ++te) {
    short8 pa = *(const short8*)&plw[lr * 40 + lk4 * 8];
    short8 vb = *(const short8*)&vtw[(te * 16 + lr) * 40 + lk4 * 8];
    o[te] = mfma16(pa, vb, z);
  }
#pragma unroll
  for (int te = 0; te < 2; ++te)
#pragma unroll
    for (int r = 0; r < 4; ++r) {
      int n = lk4 * 4 + r;
      olw[n * 33 + te * 16 + lr] = o[te][r] * invden[r];
    }
  wave_lds_fence();
  // store: lane = (token lr) x (e-chunk lk4)
  {
    int h = h0 + (lr >> 2), w = w0 + (lr & 3);
    size_t base = ((size_t)(Bg >> 2)) * 4194304 +
                  (size_t)(((Bg & 3) * 2 + (h >> 5))) * 131072 +
                  (size_t)(((h >> 2) & 7)) * 16384 + (size_t)((h & 3) * 64 + w);
#pragma unroll
    for (int ee = 0; ee < 8; ++ee) {
      int e = lk4 * 8 + ee;
      int c = g * 32 + e;
      size_t idx = base + (size_t)(c >> 6) * 1048576 + (size_t)((c >> 3) & 7) * 2048 +
                   (size_t)(c & 7) * 256;
      out[idx] = olw[lr * 33 + e];
    }
  }
}

extern "C" void kernel_launch(void* const* d_in, const int* in_sizes, int n_in,
                              void* d_out, int out_size, void* d_ws, size_t ws_size,
                              hipStream_t stream) {
  const float* x = (const float*)d_in[0];
  const float* qkv_w = (const float*)d_in[1];
  const float* qkv_b = (const float*)d_in[2];
  const float* t0 = (const float*)d_in[3];
  const float* t1 = (const float*)d_in[4];
  float* out = (float*)d_out;
  char* ws = (char*)d_ws;

  u16* qkvB = (u16*)ws;                         // 192*65536*4 u16  = 100663296 B
  u16* wbp = (u16*)(ws + 100663296);            // 196608 u16       = 393216 B
  float* bias8 = (float*)(ws + 101056512);      // 4*64*64*4        = 65536 B
  float* bias4 = (float*)(ws + 101122048);      // 4*16*16*4        = 4096 B

  k_prep<<<256, 256, 0, stream>>>(qkv_w, t0, t1, wbp, bias4, bias8);
  k_gemm<<<2048, 512, 0, stream>>>(x, wbp, qkv_b, qkvB);
  k_attn8<<<4096, 64, 0, stream>>>(qkvB, bias8, out);
  k_attn4<<<16384, 64, 0, stream>>>(qkvB, bias4, out);
}

// Round 18
// 93.772 us; speedup vs baseline: 1.1395x; 1.0161x over previous
//
#include <hip/hip_runtime.h>

typedef unsigned short u16;
typedef unsigned int u32;
typedef __attribute__((ext_vector_type(8))) short short8;   // 8 bf16 (MFMA A/B frag)
typedef __attribute__((ext_vector_type(4))) float f32x4;    // MFMA C/D frag
typedef __attribute__((ext_vector_type(4))) float fvec4;
typedef __attribute__((ext_vector_type(4))) u16 u16x4;

typedef __attribute__((address_space(1))) void gvoid;
typedef __attribute__((address_space(3))) void lvoid;

__device__ __forceinline__ u16 f2bf(float f) {
  u32 u = __float_as_uint(f);
  u += 0x7FFFu + ((u >> 16) & 1u);   // RTNE
  return (u16)(u >> 16);
}

// async global->LDS DMA, 16B/lane: LDS dest = uniform base + lane*16, global src per-lane.
__device__ __forceinline__ void gl16(const u16* g, u16* d) {
  __builtin_amdgcn_global_load_lds((gvoid*)g, (lvoid*)d, 16, 0, 0);
}

// wave-local LDS fence: drains this wave's ds ops only (lgkmcnt), does NOT touch vmcnt.
__device__ __forceinline__ void wave_lds_fence() {
  asm volatile("s_waitcnt lgkmcnt(0)" ::: "memory");
  __builtin_amdgcn_sched_barrier(0);
}

// memory row index of token (Bg,h,w); rows of x are 256 elems.
__device__ __forceinline__ int m_of(int Bg, int h, int w) {
  return ((Bg >> 2) << 14) | ((h & 3) << 12) | ((((Bg & 3) << 1) | (h >> 5)) << 9) |
         (((h >> 2) & 7) << 6) | w;
}

__device__ __forceinline__ f32x4 mfma16(short8 a, short8 b, f32x4 c) {
  return __builtin_amdgcn_mfma_f32_16x16x32_bf16(a, b, c, 0, 0, 0);
}

// qkvB blocked layout: element (channel c, token m) lives at (c>>2)*262144 + m*4 + (c&3).
__device__ __forceinline__ short8 ld8(const u16* __restrict__ qb, int c4, int m) {
  union { u16x4 h[2]; short8 v; } u;
  u.h[0] = *(const u16x4*)(qb + (size_t)c4 * 262144 + (size_t)m * 4);
  u.h[1] = *(const u16x4*)(qb + (size_t)(c4 + 1) * 262144 + (size_t)m * 4);
  return u.v;
}

// ---------------- prep: pack W into DMA-ready swizzled order + bias matrices --------------
__global__ void k_prep(const float* __restrict__ qkv_w, const float* __restrict__ t0,
                       const float* __restrict__ t1, u16* __restrict__ wbp,
                       float* __restrict__ bias4, float* __restrict__ bias8) {
  int tid = blockIdx.x * 256 + threadIdx.x;
  int stride = gridDim.x * 256;
  for (int i = tid; i < 196608; i += stride) {
    int nhc = i / 12288;              // (nh*8 + chunk) in [0,16)
    int rem = i - nhc * 12288;
    int p = rem >> 3, e = rem & 7;
    int cu = p >> 2;
    int su = (p & 3) ^ ((cu >> 1) & 3);
    int col = (nhc >> 3) * 384 + cu;
    int k = (nhc & 7) * 32 + su * 8 + e;
    wbp[i] = f2bf(qkv_w[col * 256 + k]);
  }
  for (int i = tid; i < 4 * 64 * 64; i += stride) {
    int g = i >> 12, n = (i >> 6) & 63, m = i & 63;
    int di = (n >> 3) - (m >> 3) + 7, dj = (n & 7) - (m & 7) + 7;
    bias8[i] = t1[(di * 15 + dj) * 4 + g];
  }
  for (int i = tid; i < 4 * 16 * 16; i += stride) {
    int g = i >> 8, n = (i >> 4) & 15, m = i & 15;
    int di = (n >> 2) - (m >> 2) + 3, dj = (n & 3) - (m & 3) + 3;
    bias4[i] = t0[(di * 7 + dj) * 4 + g];
  }
}

// ---------------- QKV GEMM: [65536 x 256] x [256 x 768] -> qkvB blocked layout ------------
// Grid 2048, pairing swizzle (col-half pairs share an XCD -> x tile L2-hit). ROUND-18:
// FULL As 64x256 (32KB, slot-swizzled) -> no K-half restage, no mid-loop barriers; after
// the single prologue barrier the 8 waves free-run the DMA pipeline. LDS = 32K + 48K =
// exactly 80KB -> 2 blocks/CU. B via global_load_lds from pre-swizzled wbp, per-wave dbuf
// slabs, 2-deep counted vmcnt(3) (proven r15). Bias pre-loaded & pinned (oldest VMEM).
__global__ __launch_bounds__(512, 4) void k_gemm(const float* __restrict__ x,
                                                 const u16* __restrict__ wbp,
                                                 const float* __restrict__ qkv_b,
                                                 u16* __restrict__ qkvB) {
  __shared__ __align__(16) u16 As[64 * 256];       // 32768 B, XOR slot-swizzled, full K
  __shared__ __align__(16) u16 Bs[2 * 8 * 1536];   // 49152 B: [buf][wave][48 cols x 32 k]
  const int t = threadIdx.x;
  const int wid = t >> 6, l = t & 63;
  const int lr = l & 15, lk4 = l >> 4;
  const int mt = ((blockIdx.x >> 4) << 3) | (blockIdx.x & 7);  // pairing swizzle
  const int nh = (blockIdx.x >> 3) & 1;
  const size_t xbase = (size_t)mt * 64 * 256;
  const int colbase = nh * 384;            // this block's first output col

  // B DMA geometry: src has per-lane l*8; dest base is wave-uniform (HW adds lane*16B)
  const u16* wsrc = wbp + (size_t)(nh * 8) * 12288 + (wid * 192 + l) * 8;
  u16* bdst = &Bs[wid * 1536];

  // ---- (1) bias pre-load: OLDEST VMEM, pinned before any DMA ----
  fvec4 bb[3];
#pragma unroll
  for (int jt = 0; jt < 3; ++jt)
    bb[jt] = *(const fvec4*)(qkv_b + colbase + wid * 48 + jt * 16 + lk4 * 4);
  asm volatile("" ::: "memory");           // bias loads stay above everything below

  // ---- (2) DMA chunk0 -> buf0, chunk1 -> buf1 ----
#pragma unroll
  for (int j = 0; j < 3; ++j) gl16(wsrc + j * 512, bdst + j * 512);
#pragma unroll
  for (int j = 0; j < 3; ++j) gl16(wsrc + 12288 + j * 512, bdst + 12288 + j * 512);
  asm volatile("" ::: "memory");           // pin DMA issue order before x loads

  // ---- (3) stage FULL As: thread covers col (t&63)*4, rows wid + it*8 (r8 pattern) ----
  {
    const int cc = (l & 63) * 4;           // u16 col, multiple of 4
    const int slot = cc >> 3, half = cc & 7;
    const float* xp = x + xbase + (size_t)wid * 256 + cc;
#pragma unroll
    for (int it = 0; it < 8; ++it) {
      fvec4 v = *(const fvec4*)(xp + it * 8 * 256);
      int r = wid + it * 8;
      u16x4 u;
      u[0] = f2bf(v[0]); u[1] = f2bf(v[1]); u[2] = f2bf(v[2]); u[3] = f2bf(v[3]);
      *(u16x4*)&As[r * 256 + ((slot ^ (r & 7)) << 3) + half] = u;
    }
  }
  asm volatile("s_waitcnt lgkmcnt(0)" ::: "memory");
  __builtin_amdgcn_s_barrier();            // As visible — the ONLY barrier in this kernel

  f32x4 acc[3][4];
  const f32x4 z = {0.f, 0.f, 0.f, 0.f};
#pragma unroll
  for (int jt = 0; jt < 3; ++jt)
#pragma unroll
    for (int rt = 0; rt < 4; ++rt) acc[jt][rt] = z;

  const int bswz = (lr >> 1) & 3;          // B-read slot swizzle
#pragma unroll
  for (int ci = 0; ci < 8; ++ci) {
    const int buf = ci & 1;
    // counted wait: chunk ci is the 2nd-newest DMA group in FIFO -> vmcnt(3) retires it;
    // chunk ci+1 (newest, 3 ops) stays in flight. Last iter: full drain.
    if (ci == 7) asm volatile("s_waitcnt vmcnt(0)" ::: "memory");
    else         asm volatile("s_waitcnt vmcnt(3)" ::: "memory");
    __builtin_amdgcn_sched_barrier(0);
    // reads (LDS only)
    short8 a[4], b[3];
    const int kslot = ci * 4 + lk4;        // 0..31 within full 256-K row
#pragma unroll
    for (int rt = 0; rt < 4; ++rt) {
      int row = rt * 16 + lr;
      a[rt] = *(const short8*)&As[row * 256 + ((kslot ^ (row & 7)) << 3)];
    }
#pragma unroll
    for (int jt = 0; jt < 3; ++jt)
      b[jt] = *(const short8*)&Bs[buf * 12288 + wid * 1536 +
                                  (jt * 16 + lr) * 32 + ((lk4 ^ bswz) * 8)];
    // drain reads into regs -> WAR-safe to DMA into this buffer below
    asm volatile("s_waitcnt lgkmcnt(0)" ::: "memory");
    __builtin_amdgcn_sched_barrier(0);
    if (ci < 6) {                          // issue chunk ci+2 into buf(ci&1)
      const u16* s = wsrc + (size_t)(ci + 2) * 12288;
      u16* d = bdst + buf * 12288;
#pragma unroll
      for (int j = 0; j < 3; ++j) gl16(s + j * 512, d + j * 512);
    }
    __builtin_amdgcn_sched_barrier(0);
#pragma unroll
    for (int jt = 0; jt < 3; ++jt)
#pragma unroll
      for (int rt = 0; rt < 4; ++rt)
        acc[jt][rt] = mfma16(b[jt], a[rt], acc[jt][rt]);  // reg-dim = col
  }

  // ---- epilogue: + pre-loaded bias, blocked layout -> per-lane u16x4, coalesced ----
  const int rows0 = mt * 64;
#pragma unroll
  for (int jt = 0; jt < 3; ++jt) {
    int col0 = colbase + wid * 48 + jt * 16 + lk4 * 4;
    int c40 = col0 >> 2;
#pragma unroll
    for (int rt = 0; rt < 4; ++rt) {
      int row = rows0 + rt * 16 + lr;
      u16x4 u;
#pragma unroll
      for (int r = 0; r < 4; ++r) u[r] = f2bf(acc[jt][rt][r] + bb[jt][r]);
      *(u16x4*)&qkvB[(size_t)c40 * 262144 + (size_t)row * 4] = u;
    }
  }
}

// ---------------- merged attention: blocks [0,4096) = ws=8, [4096,20480) = ws=4 ----------
// 1-wave blocks, XCD-chunked swizzles, per-wave LDS carve; no barriers anywhere.
__global__ __launch_bounds__(64) void k_attn(const u16* __restrict__ qkvB,
                                             const float* __restrict__ bias8,
                                             const float* __restrict__ bias4,
                                             float* __restrict__ out) {
  __shared__ __align__(16) u16 sbuf[6912];   // 13824 B: max(attn8 = 2304+4608, attn4)
  const int l = threadIdx.x;
  const int lr = l & 15, lk4 = l >> 4;
  const f32x4 z = {0.f, 0.f, 0.f, 0.f};
  const float scale = 0.17677669529663687f;  // 1/sqrt(32)

  if (blockIdx.x < 4096) {
    // ================= ws = 8 (group 1, channels 128..255) =================
    u16* vtg = sbuf;                 // V^T [e][m] stride 72 (2304 u16)
    u16* plg = sbuf + 2304;          // P [n][m] stride 72; reused as O f32 [64][33]
    const int lid = blockIdx.x;
    const int logical = (lid & 7) * 512 + (lid >> 3);  // bijective: 4096 = 8*512
    const int g = logical & 3;
    const int wj = (logical >> 2) & 7, wi = (logical >> 5) & 7, Bg = logical >> 8;
    const int h0 = wi * 8, w0 = wj * 8;

    const int c4q = 32 + g * 8 + lk4 * 2;   // q chans 128+g*32+lk4*8
    const int c4k = 96 + g * 8 + lk4 * 2;   // k chans 384+g*32+lk4*8
    short8 aq[4], bk[4];
#pragma unroll
    for (int tn = 0; tn < 4; ++tn) {
      int n = tn * 16 + lr;
      int m = m_of(Bg, h0 + (n >> 3), w0 + (n & 7));
      aq[tn] = ld8(qkvB, c4q, m);
      bk[tn] = ld8(qkvB, c4k, m);
    }
    // stage V^T: lane l owns token m=l; v chans 640+g*32 .. +31
    {
      int m = m_of(Bg, h0 + (l >> 3), w0 + (l & 7));
#pragma unroll
      for (int j2 = 0; j2 < 8; ++j2) {
        u16x4 p = *(const u16x4*)(qkvB + (size_t)(160 + g * 8 + j2) * 262144 + (size_t)m * 4);
#pragma unroll
        for (int r = 0; r < 4; ++r) vtg[(j2 * 4 + r) * 72 + l] = p[r];
      }
    }
    // S = q k^T  (16 MFMAs)
    f32x4 s[4][4];
#pragma unroll
    for (int tn = 0; tn < 4; ++tn)
#pragma unroll
      for (int tm = 0; tm < 4; ++tm) s[tn][tm] = mfma16(aq[tn], bk[tm], z);

#pragma unroll
    for (int tn = 0; tn < 4; ++tn)
#pragma unroll
      for (int tm = 0; tm < 4; ++tm)
#pragma unroll
        for (int r = 0; r < 4; ++r) {
          int n = tn * 16 + lk4 * 4 + r, m = tm * 16 + lr;
          s[tn][tm][r] = s[tn][tm][r] * scale + bias8[(g * 64 + n) * 64 + m];
        }
    // softmax over m (row n lives in 16 lanes sharing l>>4)
    float invden[4][4];
#pragma unroll
    for (int tn = 0; tn < 4; ++tn)
#pragma unroll
      for (int r = 0; r < 4; ++r) {
        float mx = fmaxf(fmaxf(s[tn][0][r], s[tn][1][r]), fmaxf(s[tn][2][r], s[tn][3][r]));
#pragma unroll
        for (int d = 1; d < 16; d <<= 1) mx = fmaxf(mx, __shfl_xor(mx, d));
        float sum = 0.f;
#pragma unroll
        for (int tm = 0; tm < 4; ++tm) {
          float p = __expf(s[tn][tm][r] - mx);
          s[tn][tm][r] = p;
          sum += p;
        }
#pragma unroll
        for (int d = 1; d < 16; d <<= 1) sum += __shfl_xor(sum, d);
        invden[tn][r] = 1.f / sum;
      }
    // P -> LDS (bf16)
#pragma unroll
    for (int tn = 0; tn < 4; ++tn)
#pragma unroll
      for (int tm = 0; tm < 4; ++tm)
#pragma unroll
        for (int r = 0; r < 4; ++r)
          plg[(tn * 16 + lk4 * 4 + r) * 72 + tm * 16 + lr] = f2bf(s[tn][tm][r]);
    wave_lds_fence();
    // O = P V  (16 MFMAs)
    f32x4 o[4][2];
#pragma unroll
    for (int tn = 0; tn < 4; ++tn) { o[tn][0] = z; o[tn][1] = z; }
#pragma unroll
    for (int kc = 0; kc < 2; ++kc) {
      short8 pa[4], vb[2];
#pragma unroll
      for (int tn = 0; tn < 4; ++tn)
        pa[tn] = *(const short8*)&plg[(tn * 16 + lr) * 72 + kc * 32 + lk4 * 8];
#pragma unroll
      for (int te = 0; te < 2; ++te)
        vb[te] = *(const short8*)&vtg[(te * 16 + lr) * 72 + kc * 32 + lk4 * 8];
#pragma unroll
      for (int tn = 0; tn < 4; ++tn)
#pragma unroll
        for (int te = 0; te < 2; ++te) o[tn][te] = mfma16(pa[tn], vb[te], o[tn][te]);
    }
    wave_lds_fence();
    // scale by 1/denom, transpose O through LDS (overlay on plg)
    float* ol = (float*)plg;  // [64][33]
#pragma unroll
    for (int tn = 0; tn < 4; ++tn)
#pragma unroll
      for (int te = 0; te < 2; ++te)
#pragma unroll
        for (int r = 0; r < 4; ++r) {
          int n = tn * 16 + lk4 * 4 + r;
          ol[n * 33 + te * 16 + lr] = o[tn][te][r] * invden[tn][r];
        }
    wave_lds_fence();
    // store: lane = token, loop e -> 32B-chunk runs along w
    {
      int h = h0 + (l >> 3), w = w0 + (l & 7);
      size_t base = ((size_t)(Bg >> 2)) * 4194304 + (size_t)(((Bg & 3) * 2 + (h >> 5))) * 131072 +
                    (size_t)(((h >> 2) & 7)) * 16384 + (size_t)((h & 3) * 64 + w);
#pragma unroll
      for (int e = 0; e < 32; ++e) {
        int c = 128 + g * 32 + e;
        size_t idx = base + (size_t)(c >> 6) * 1048576 + (size_t)((c >> 3) & 7) * 2048 +
                     (size_t)(c & 7) * 256;
        out[idx] = ol[l * 33 + e];
      }
    }
  } else {
    // ================= ws = 4 (group 0, channels 0..127) =================
    u16* vtw = sbuf;                       // V^T [e][m0..32] stride 40 (1280 u16)
    u16* plw = sbuf + 1280;                // P [n][m0..32] stride 40 (640 u16)
    float* olw = (float*)(sbuf + 1920);    // O [16][33] f32 (4B-aligned: 3840%4==0)
    const int lid = blockIdx.x - 4096;
    const int logical = (lid & 7) * 2048 + (lid >> 3);  // bijective: 16384 = 8*2048
    const int g = logical & 3;
    const int wid2 = logical >> 2;         // window id in [0,4096)
    const int Bg = wid2 >> 8, wi = (wid2 >> 4) & 15, wj = wid2 & 15;
    const int h0 = wi * 4, w0 = wj * 4;
    const short8 z8 = {0, 0, 0, 0, 0, 0, 0, 0};

    // zero the K-padding (cols 16..31) of P and V^T
    {
      u16x4 z4 = {0, 0, 0, 0};
      *(u16x4*)&plw[(l & 15) * 40 + 16 + (l >> 4) * 4] = z4;
      *(short8*)&vtw[(l >> 1) * 40 + 16 + (l & 1) * 8] = z8;
    }
    const int mq = m_of(Bg, h0 + (lr >> 2), w0 + (lr & 3));

    short8 aq = ld8(qkvB, g * 8 + lk4 * 2, mq);          // q chans g*32+lk4*8
    short8 bk = ld8(qkvB, 64 + g * 8 + lk4 * 2, mq);     // k chans 256+g*32+lk4*8
    {
      short8 v = ld8(qkvB, 128 + g * 8 + lk4 * 2, mq);   // v chans 512+g*32+lk4*8
#pragma unroll
      for (int j = 0; j < 8; ++j) vtw[(lk4 * 8 + j) * 40 + lr] = (u16)v[j];
    }
    // S (1 MFMA), C rows n = lk4*4+r, cols m = lr
    f32x4 s = mfma16(aq, bk, z);
#pragma unroll
    for (int r = 0; r < 4; ++r) {
      int n = lk4 * 4 + r;
      s[r] = s[r] * scale + bias4[(g * 16 + n) * 16 + lr];
    }
    float invden[4];
#pragma unroll
    for (int r = 0; r < 4; ++r) {
      float mx = s[r];
#pragma unroll
      for (int d = 1; d < 16; d <<= 1) mx = fmaxf(mx, __shfl_xor(mx, d));
      float p = __expf(s[r] - mx);
      s[r] = p;
      float sum = p;
#pragma unroll
      for (int d = 1; d < 16; d <<= 1) sum += __shfl_xor(sum, d);
      invden[r] = 1.f / sum;
    }
    // P -> LDS
#pragma unroll
    for (int r = 0; r < 4; ++r) plw[(lk4 * 4 + r) * 40 + lr] = f2bf(s[r]);
    wave_lds_fence();
    // O = P V : 2 MFMAs (te halves), K zero-padded to 32
    f32x4 o[2];
#pragma unroll
    for (int te = 0; te < 2; ++te) {
      short8 pa = *(const short8*)&plw[lr * 40 + lk4 * 8];
      short8 vb = *(const short8*)&vtw[(te * 16 + lr) * 40 + lk4 * 8];
      o[te] = mfma16(pa, vb, z);
    }
#pragma unroll
    for (int te = 0; te < 2; ++te)
#pragma unroll
      for (int r = 0; r < 4; ++r) {
        int n = lk4 * 4 + r;
        olw[n * 33 + te * 16 + lr] = o[te][r] * invden[r];
      }
    wave_lds_fence();
    // store: lane = (token lr) x (e-chunk lk4)
    {
      int h = h0 + (lr >> 2), w = w0 + (lr & 3);
      size_t base = ((size_t)(Bg >> 2)) * 4194304 +
                    (size_t)(((Bg & 3) * 2 + (h >> 5))) * 131072 +
                    (size_t)(((h >> 2) & 7)) * 16384 + (size_t)((h & 3) * 64 + w);
#pragma unroll
      for (int ee = 0; ee < 8; ++ee) {
        int e = lk4 * 8 + ee;
        int c = g * 32 + e;
        size_t idx = base + (size_t)(c >> 6) * 1048576 + (size_t)((c >> 3) & 7) * 2048 +
                     (size_t)(c & 7) * 256;
        out[idx] = olw[lr * 33 + e];
      }
    }
  }
}

extern "C" void kernel_launch(void* const* d_in, const int* in_sizes, int n_in,
                              void* d_out, int out_size, void* d_ws, size_t ws_size,
                              hipStream_t stream) {
  const float* x = (const float*)d_in[0];
  const float* qkv_w = (const float*)d_in[1];
  const float* qkv_b = (const float*)d_in[2];
  const float* t0 = (const float*)d_in[3];
  const float* t1 = (const float*)d_in[4];
  float* out = (float*)d_out;
  char* ws = (char*)d_ws;

  u16* qkvB = (u16*)ws;                         // 192*65536*4 u16  = 100663296 B
  u16* wbp = (u16*)(ws + 100663296);            // 196608 u16       = 393216 B
  float* bias8 = (float*)(ws + 101056512);      // 4*64*64*4        = 65536 B
  float* bias4 = (float*)(ws + 101122048);      // 4*16*16*4        = 4096 B

  k_prep<<<256, 256, 0, stream>>>(qkv_w, t0, t1, wbp, bias4, bias8);
  k_gemm<<<2048, 512, 0, stream>>>(x, wbp, qkv_b, qkvB);
  k_attn<<<20480, 64, 0, stream>>>(qkvB, bias8, bias4, out);
}